// Round 13
// baseline (276.312 us; speedup 1.0000x reference)
//
#include <hip/hip_runtime.h>
#include <cstdint>
#include <cstddef>

// ---------------------------------------------------------------------------
// MultiHeadAttention: x(4,2048,1024) @ W_qkv -> causal MHA (16 heads, d=64)
// -> @ W_out. fp32 in/out, fp16 MFMA internally (threshold 7.5e-2).
// R12 (271.2us): 4-wave QT=128 flash, proven 2-barrier schedule; Q-prescale,
//      cvt_pkrtz, setprio.
// R15 (263.2us): flash KT=128 (17 iters, halved lockstep events) + raw
//      v_exp_f32. flash now <75us; top kernel is gemm_qkv 75.2us
//      (685 TF, Mfma 28 / VALU 13 / HBM 21).
// R16: FUSE CAST INTO gemm_qkv. cast_f32_f16 (~9us + launch gap) deleted;
//      gemm_qkv stages A as fp32 straight from x via global_load_lds and
//      converts f32->f16 at frag load (VALU has headroom at 13%).
//      Bank-conflict handling per rule-21: linear gll dest + XOR-pre-
//      swizzled SOURCE chunk (chunk ^ row&7) + same XOR on the LDS read.
//      No sync-structure change. LDS: A-f32 16KB + B 8KB fits existing
//      33.8KB smem; V-transpose epilogue untouched.
// R17: resubmit of R16 (R12-round bench was acquisition timeout — infra).
// ---------------------------------------------------------------------------

#define D_MODEL 1024
#define NHEADS  16
#define DHEAD   64
#define BATCH   4
#define SEQ     2048

typedef __attribute__((ext_vector_type(8))) _Float16 half8;
typedef __attribute__((ext_vector_type(4))) _Float16 half4;
typedef __attribute__((ext_vector_type(4))) float    f32x4;

__device__ __forceinline__ void async_copy16(const _Float16* g, _Float16* l) {
    __builtin_amdgcn_global_load_lds(
        (const __attribute__((address_space(1))) uint32_t*)g,
        (__attribute__((address_space(3))) uint32_t*)l, 16, 0, 0);
}

__device__ __forceinline__ void async_copy16f(const float* g, float* l) {
    __builtin_amdgcn_global_load_lds(
        (const __attribute__((address_space(1))) uint32_t*)g,
        (__attribute__((address_space(3))) uint32_t*)l, 16, 0, 0);
}

__device__ __forceinline__ float fast_exp2(float x) {
#if __has_builtin(__builtin_amdgcn_exp2f)
    return __builtin_amdgcn_exp2f(x);   // raw v_exp_f32; -inf -> 0
#else
    return exp2f(x);
#endif
}

// ---------------------------------------------------------------------------
// 1. tiled transpose + cast: (R x C) fp32 -> (C x R) fp16
// ---------------------------------------------------------------------------
__global__ void transpose_cast(const float* __restrict__ in,
                               _Float16* __restrict__ out, int R, int C) {
    __shared__ float tile[32][33];
    int c0 = blockIdx.x * 32, r0 = blockIdx.y * 32;
    int tx = threadIdx.x, ty = threadIdx.y;
    #pragma unroll
    for (int i = 0; i < 32; i += 8)
        tile[ty + i][tx] = in[(size_t)(r0 + ty + i) * C + c0 + tx];
    __syncthreads();
    #pragma unroll
    for (int i = 0; i < 32; i += 8)
        out[(size_t)(c0 + ty + i) * R + r0 + tx] = (_Float16)tile[tx][ty + i];
}

// ---------------------------------------------------------------------------
// 2. QKV GEMM: x[8192][1024] (fp32, cast fused) @ WqT[3072][1024]^T.
//    A staged fp32 via global_load_lds with XOR-chunk-swizzled source
//    (conflict-managed b128 frag reads); converted f32->f16 at frag load.
//    Cols < 2048 (Q,K) -> QK[8192][2048] row-major (direct stores).
//    Cols >= 2048 (V)  -> Vtg[(b*16+h)*64+d][2048] transposed, via an LDS
//    128x132 transpose so global stores are 16B-coalesced rows.
// ---------------------------------------------------------------------------
__global__ void gemm_qkv(const float* __restrict__ Af,
                         const _Float16* __restrict__ Bt,
                         _Float16* __restrict__ QK,
                         _Float16* __restrict__ Vtg) {
    __shared__ __attribute__((aligned(16))) _Float16 smem[128 * 132];
    float*    Asf = (float*)smem;          // 128 x 32 fp32, chunk-swizzled (16KB)
    _Float16* Bs  = smem + 8192;           // 128 x 32 fp16 (8KB); ends at 12288 < 16896

    const int tid  = threadIdx.x;
    const int w    = tid >> 6, lane = tid & 63;
    const int l15  = lane & 15, quad = lane >> 4;
    const int wm   = w >> 1, wn = w & 1;
    const int row0 = blockIdx.y * 128, col0 = blockIdx.x * 128;
    const int K = 1024;

    f32x4 acc[4][4];
    #pragma unroll
    for (int i = 0; i < 4; i++)
        #pragma unroll
        for (int j = 0; j < 4; j++)
            acc[i][j] = (f32x4){0.f, 0.f, 0.f, 0.f};

    // B staging indices (fp16, unchanged pattern)
    const int r0i = tid >> 2, c0i = tid & 3;
    const int r1i = (256 + tid) >> 2;
    // A staging indices (fp32): lane covers 4 floats (16B)
    const int lr       = lane >> 3;          // 0..7 row within wave's 8-row band
    const int srcChunk = (lane & 7) ^ lr;    // pre-swizzled source chunk

    for (int k0 = 0; k0 < K; k0 += 32) {
        __syncthreads();
        #pragma unroll
        for (int q = 0; q < 4; q++) {
            const float* g = Af + (size_t)(row0 + q * 32 + w * 8 + lr) * K
                               + k0 + srcChunk * 4;
            async_copy16f(g, &Asf[(q * 32 + w * 8) * 32]);
        }
        async_copy16(Bt + (size_t)(col0 + r0i) * K + k0 + c0i * 8, &Bs[(w * 64) * 8]);
        async_copy16(Bt + (size_t)(col0 + r1i) * K + k0 + c0i * 8, &Bs[(256 + w * 64) * 8]);
        __syncthreads();

        half8 af[4], bfm[4];
        #pragma unroll
        for (int i = 0; i < 4; i++) {
            const int arow = wm * 64 + i * 16 + l15;
            const int rs   = l15 & 7;
            f32x4 lo = *(const f32x4*)&Asf[arow * 32 + (((2 * quad)    ) ^ rs) * 4];
            f32x4 hi = *(const f32x4*)&Asf[arow * 32 + (((2 * quad) + 1) ^ rs) * 4];
            half8 a;
            a[0] = (_Float16)lo[0]; a[1] = (_Float16)lo[1];
            a[2] = (_Float16)lo[2]; a[3] = (_Float16)lo[3];
            a[4] = (_Float16)hi[0]; a[5] = (_Float16)hi[1];
            a[6] = (_Float16)hi[2]; a[7] = (_Float16)hi[3];
            af[i] = a;
        }
        #pragma unroll
        for (int j = 0; j < 4; j++)
            bfm[j] = *(const half8*)&Bs[(wn * 64 + j * 16 + l15) * 32 + quad * 8];
        #pragma unroll
        for (int i = 0; i < 4; i++)
            #pragma unroll
            for (int j = 0; j < 4; j++)
                acc[i][j] = __builtin_amdgcn_mfma_f32_16x16x32_f16(
                    af[i], bfm[j], acc[i][j], 0, 0, 0);
    }

    if (blockIdx.x < 16) {  // Q,K region: row-major into QK (ld 2048)
        #pragma unroll
        for (int i = 0; i < 4; i++) {
            int row = row0 + wm * 64 + i * 16 + quad * 4;
            #pragma unroll
            for (int j = 0; j < 4; j++) {
                int col = col0 + wn * 64 + j * 16 + l15;
                #pragma unroll
                for (int r = 0; r < 4; r++)
                    QK[(size_t)(row + r) * 2048 + col] = (_Float16)acc[i][j][r];
            }
        }
    } else {
        // V region: transpose 128x128 tile through LDS, then coalesced rows.
        __syncthreads();
        #pragma unroll
        for (int i = 0; i < 4; i++) {
            int tl = wm * 64 + i * 16 + quad * 4;
            #pragma unroll
            for (int j = 0; j < 4; j++) {
                int vl = wn * 64 + j * 16 + l15;
                half4 pk;
                #pragma unroll
                for (int r = 0; r < 4; r++) pk[r] = (_Float16)acc[i][j][r];
                *(half4*)&smem[vl * 132 + tl] = pk;
            }
        }
        __syncthreads();
        const int bb = row0 >> 11, tb = row0 & 2047;
        const int rr0 = tid >> 4;
        const int cc  = (tid & 15) * 8;
        #pragma unroll
        for (int s = 0; s < 8; s++) {
            int vl = rr0 + s * 16;
            int vcol = (col0 - 2048) + vl;
            int hh = vcol >> 6, d = vcol & 63;
            *(half8*)&Vtg[((size_t)((bb * 16 + hh) * 64 + d)) * 2048 + tb + cc] =
                *(const half8*)&smem[vl * 132 + cc];
        }
    }
}

// ---------------------------------------------------------------------------
// 3. output GEMM: Obuf[8192][1024] @ WoT[1024][1024]^T -> fp32 out
// ---------------------------------------------------------------------------
__global__ void gemm_out(const _Float16* __restrict__ A,
                         const _Float16* __restrict__ Bt,
                         float* __restrict__ Cf, int N, int K) {
    __shared__ __attribute__((aligned(16))) _Float16 As[128 * 32];
    __shared__ __attribute__((aligned(16))) _Float16 Bs[128 * 32];

    const int tid  = threadIdx.x;
    const int w    = tid >> 6, lane = tid & 63;
    const int l15  = lane & 15, quad = lane >> 4;
    const int wm   = w >> 1, wn = w & 1;
    const int row0 = blockIdx.y * 128, col0 = blockIdx.x * 128;

    f32x4 acc[4][4];
    #pragma unroll
    for (int i = 0; i < 4; i++)
        #pragma unroll
        for (int j = 0; j < 4; j++)
            acc[i][j] = (f32x4){0.f, 0.f, 0.f, 0.f};

    const int r0i = tid >> 2, c0i = tid & 3;
    const int r1i = (256 + tid) >> 2;

    for (int k0 = 0; k0 < K; k0 += 32) {
        __syncthreads();
        async_copy16(A  + (size_t)(row0 + r0i) * K + k0 + c0i * 8, &As[(w * 64) * 8]);
        async_copy16(A  + (size_t)(row0 + r1i) * K + k0 + c0i * 8, &As[(256 + w * 64) * 8]);
        async_copy16(Bt + (size_t)(col0 + r0i) * K + k0 + c0i * 8, &Bs[(w * 64) * 8]);
        async_copy16(Bt + (size_t)(col0 + r1i) * K + k0 + c0i * 8, &Bs[(256 + w * 64) * 8]);
        __syncthreads();

        half8 af[4], bfm[4];
        #pragma unroll
        for (int i = 0; i < 4; i++)
            af[i] = *(const half8*)&As[(wm * 64 + i * 16 + l15) * 32 + quad * 8];
        #pragma unroll
        for (int j = 0; j < 4; j++)
            bfm[j] = *(const half8*)&Bs[(wn * 64 + j * 16 + l15) * 32 + quad * 8];
        #pragma unroll
        for (int i = 0; i < 4; i++)
            #pragma unroll
            for (int j = 0; j < 4; j++)
                acc[i][j] = __builtin_amdgcn_mfma_f32_16x16x32_f16(
                    af[i], bfm[j], acc[i][j], 0, 0, 0);
    }

    #pragma unroll
    for (int i = 0; i < 4; i++) {
        int row = row0 + wm * 64 + i * 16 + quad * 4;
        #pragma unroll
        for (int j = 0; j < 4; j++) {
            int col = col0 + wn * 64 + j * 16 + l15;
            #pragma unroll
            for (int r = 0; r < 4; r++)
                Cf[(size_t)(row + r) * N + col] = acc[i][j][r];
        }
    }
}

// ---------------------------------------------------------------------------
// 4. Flash attention (causal). QT=128 per block, 4 waves x 256 thr,
//    wave = 32 q rows (2 groups), KT=128 (17 iters). Pairing (pr, 15-pr);
//    grid 512 = 2 blocks/CU. Proven sync template per iter: {bar;
//    ds_write K/V tile; bar; reg-prefetch next tile; compute}. K tile
//    128x64 (rows=kv), V tile 64x128 (rows=d). Q pre-scaled by log2(e)/8;
//    raw v_exp_f32; cvt_pkrtz P-packing; setprio around MFMA. S^T layout
//    (A=K, B=Q). QK processed in two nt-halves to cap st liveness.
// ---------------------------------------------------------------------------
#define PREFETCH(t)                                                          \
    do {                                                                     \
        const _Float16* kp_ = kb + (size_t)((t) * 128 + srow) * 2048 + sc;   \
        kr0 = *(const half8*)kp_;                                            \
        kr1 = *(const half8*)(kp_ + (size_t)32 * 2048);                      \
        kr2 = *(const half8*)(kp_ + (size_t)64 * 2048);                      \
        kr3 = *(const half8*)(kp_ + (size_t)96 * 2048);                      \
        const _Float16* vp_ = vb + (size_t)srow * 2048 + (t) * 128 + sc;     \
        vr0 = *(const half8*)vp_;                                            \
        vr1 = *(const half8*)(vp_ + 64);                                     \
        vr2 = *(const half8*)(vp_ + (size_t)32 * 2048);                      \
        vr3 = *(const half8*)(vp_ + (size_t)32 * 2048 + 64);                 \
    } while (0)

__global__ __launch_bounds__(256, 2) void flash_attn(
        const _Float16* __restrict__ qk, const _Float16* __restrict__ vt,
        _Float16* __restrict__ obuf) {
    const int pr = blockIdx.x, h = blockIdx.y, b = blockIdx.z;
    const int tid = threadIdx.x;
    const int w = tid >> 6, lane = tid & 63;
    const int l15 = lane & 15, quad = lane >> 4;

    __shared__ __attribute__((aligned(16))) _Float16 Ks[128 * 72];   // rows=kv, cols=d
    __shared__ __attribute__((aligned(16))) _Float16 Vs[64 * 136];   // rows=d,  cols=kv
    __shared__ __attribute__((aligned(16))) _Float16 Pl[4][32 * 136];

    const _Float16* kb = qk + (size_t)b * SEQ * 2048 + D_MODEL + h * 64;
    const _Float16* vb = vt + (size_t)(b * 16 + h) * 64 * 2048;

    const int srow = tid >> 3;        // staging row 0..31 (+32/64/96)
    const int sc   = (tid & 7) * 8;   // 16B chunk within 64-elem row

    const _Float16 QSCL = (_Float16)0.18033688f;  // log2(e)/sqrt(64)

    #pragma unroll 1
    for (int phase = 0; phase < 2; ++phase) {
        const int tq = phase ? (15 - pr) : pr;
        const int q0 = tq * 128;
        const int n_iter = tq + 1;          // KT=128 tiles

        // Q as MFMA B-frag: B[n=q][k=d], 2 groups x 2 k-frags, pre-scaled
        half8 qf[2][2];
        #pragma unroll
        for (int g = 0; g < 2; g++) {
            const _Float16* qp = qk
                + ((size_t)(b * SEQ + q0 + w * 32 + g * 16 + l15)) * 2048
                + h * DHEAD + quad * 8;
            qf[g][0] = *(const half8*)qp;
            qf[g][1] = *(const half8*)(qp + 32);
            #pragma unroll
            for (int j = 0; j < 8; j++) {
                qf[g][0][j] *= QSCL;
                qf[g][1][j] *= QSCL;
            }
        }

        f32x4 o[2][4];
        float l_acc[2] = {0.f, 0.f};
        #pragma unroll
        for (int g = 0; g < 2; g++)
            #pragma unroll
            for (int d = 0; d < 4; d++) o[g][d] = (f32x4){0.f, 0.f, 0.f, 0.f};

        half8 kr0, kr1, kr2, kr3, vr0, vr1, vr2, vr3;
        PREFETCH(0);   // tile 0 into regs

        #pragma unroll 1
        for (int it = 0; it < n_iter; ++it) {
            __syncthreads();
            *(half8*)&Ks[(srow      ) * 72 + sc] = kr0;
            *(half8*)&Ks[(srow + 32 ) * 72 + sc] = kr1;
            *(half8*)&Ks[(srow + 64 ) * 72 + sc] = kr2;
            *(half8*)&Ks[(srow + 96 ) * 72 + sc] = kr3;
            *(half8*)&Vs[srow * 136 + sc]             = vr0;
            *(half8*)&Vs[srow * 136 + sc + 64]        = vr1;
            *(half8*)&Vs[(srow + 32) * 136 + sc]      = vr2;
            *(half8*)&Vs[(srow + 32) * 136 + sc + 64] = vr3;
            __syncthreads();

            if (it + 1 < n_iter) PREFETCH(it + 1);

            // S^T = K Q^T, two nt-halves of 4 (kv 0..63, 64..127); K frags
            // read once per half, reused across both q-groups.
            #pragma unroll
            for (int hh = 0; hh < 2; hh++) {
                f32x4 st[2][4];
                __builtin_amdgcn_s_setprio(1);
                #pragma unroll
                for (int n4 = 0; n4 < 4; n4++) {
                    const int nt = hh * 4 + n4;
                    half8 ka0 = *(const half8*)&Ks[(nt * 16 + l15) * 72 + quad * 8];
                    half8 ka1 = *(const half8*)&Ks[(nt * 16 + l15) * 72 + 32 + quad * 8];
                    #pragma unroll
                    for (int g = 0; g < 2; g++) {
                        f32x4 acc = (f32x4){0.f, 0.f, 0.f, 0.f};
                        acc = __builtin_amdgcn_mfma_f32_16x16x32_f16(ka0, qf[g][0], acc, 0, 0, 0);
                        acc = __builtin_amdgcn_mfma_f32_16x16x32_f16(ka1, qf[g][1], acc, 0, 0, 0);
                        st[g][n4] = acc;
                    }
                }
                __builtin_amdgcn_s_setprio(0);

                // causal mask (partial tiles only) + exp2 + P -> LDS (b64).
                // Dead groups fall into the mask path and store zeros.
                #pragma unroll
                for (int g = 0; g < 2; g++) {
                    const int c0 = __builtin_amdgcn_readfirstlane(
                        q0 + w * 32 + g * 16 - 128 * it);
                    if (c0 < 127) {
                        #pragma unroll
                        for (int n4 = 0; n4 < 4; n4++)
                            #pragma unroll
                            for (int r = 0; r < 4; r++)
                                if ((hh * 4 + n4) * 16 + quad * 4 + r - l15 > c0)
                                    st[g][n4][r] = -INFINITY;
                    }
                    #pragma unroll
                    for (int n4 = 0; n4 < 4; n4++) {
                        const int nt = hh * 4 + n4;
                        float p0 = fast_exp2(st[g][n4][0]);
                        float p1 = fast_exp2(st[g][n4][1]);
                        float p2 = fast_exp2(st[g][n4][2]);
                        float p3 = fast_exp2(st[g][n4][3]);
                        l_acc[g] += (p0 + p1) + (p2 + p3);
                        auto lo = __builtin_amdgcn_cvt_pkrtz(p0, p1);
                        auto hi = __builtin_amdgcn_cvt_pkrtz(p2, p3);
                        half4 pk;
                        pk[0] = (_Float16)lo[0]; pk[1] = (_Float16)lo[1];
                        pk[2] = (_Float16)hi[0]; pk[3] = (_Float16)hi[1];
                        *(half4*)&Pl[w][(g * 16 + l15) * 136 + nt * 16 + quad * 4] = pk;
                    }
                }
            }
            asm volatile("s_waitcnt lgkmcnt(0)" ::: "memory");  // same-wave RAW

            // O += P V : V frags read once, reused across both q-groups.
            __builtin_amdgcn_s_setprio(1);
            #pragma unroll
            for (int kf = 0; kf < 4; kf++) {
                half8 pf0 = *(const half8*)&Pl[w][l15 * 136 + kf * 32 + quad * 8];
                half8 pf1 = *(const half8*)&Pl[w][(16 + l15) * 136 + kf * 32 + quad * 8];
                #pragma unroll
                for (int dt = 0; dt < 4; dt++) {
                    half8 vf = *(const half8*)&Vs[(dt * 16 + l15) * 136 + kf * 32 + quad * 8];
                    o[0][dt] = __builtin_amdgcn_mfma_f32_16x16x32_f16(pf0, vf, o[0][dt], 0, 0, 0);
                    o[1][dt] = __builtin_amdgcn_mfma_f32_16x16x32_f16(pf1, vf, o[1][dt], 0, 0, 0);
                }
            }
            __builtin_amdgcn_s_setprio(0);
        }

        // epilogue per group: reduce l over quads, divide, store fp16
        #pragma unroll
        for (int g = 0; g < 2; g++) {
            float l = l_acc[g];
            l += __shfl_xor(l, 16);
            l += __shfl_xor(l, 32);   // every lane: L[q = l15]
            float linv[4];
            #pragma unroll
            for (int r = 0; r < 4; r++)
                linv[r] = 1.0f / __shfl(l, quad * 4 + r, 16);

            _Float16* ob = obuf
                + ((size_t)(b * SEQ + q0 + w * 32 + g * 16 + quad * 4)) * D_MODEL
                + h * DHEAD;
            #pragma unroll
            for (int r = 0; r < 4; r++) {
                #pragma unroll
                for (int dt = 0; dt < 4; dt++)
                    ob[(size_t)r * D_MODEL + dt * 16 + l15] =
                        (_Float16)(o[g][dt][r] * linv[r]);
            }
        }
        __syncthreads();  // protect Ks/Vs before next phase's first stage
    }
}

// ---------------------------------------------------------------------------
// launch
// ---------------------------------------------------------------------------
extern "C" void kernel_launch(void* const* d_in, const int* in_sizes, int n_in,
                              void* d_out, int out_size, void* d_ws, size_t ws_size,
                              hipStream_t stream) {
    const float* x    = (const float*)d_in[0];
    const float* Wqkv = (const float*)d_in[1];
    const float* Wout = (const float*)d_in[2];
    float* out = (float*)d_out;

    char* ws = (char*)d_ws;
    _Float16* WqT  = (_Float16*)(ws + ((size_t)16 << 20));     //  6 MB
    _Float16* WoT  = (_Float16*)(ws + ((size_t)23 << 20));     //  2 MB
    _Float16* QKb  = (_Float16*)(ws + ((size_t)26 << 20));     // 32 MB
    _Float16* Vtg  = (_Float16*)(ws + ((size_t)58 << 20));     // 16 MB
    _Float16* Obuf = (_Float16*)(ws + ((size_t)74 << 20));     // 16 MB -> 90 MB

    transpose_cast<<<dim3(96, 32), dim3(32, 8), 0, stream>>>(Wqkv, WqT, 1024, 3072);
    transpose_cast<<<dim3(32, 32), dim3(32, 8), 0, stream>>>(Wout, WoT, 1024, 1024);
    gemm_qkv<<<dim3(24, 64), 256, 0, stream>>>(x, WqT, QKb, Vtg);
    flash_attn<<<dim3(8, NHEADS, BATCH), 256, 0, stream>>>(QKb, Vtg, Obuf);
    gemm_out<<<dim3(8, 64), 256, 0, stream>>>(Obuf, WoT, out, 1024, 1024);
}

// Round 14
// 260.290 us; speedup vs baseline: 1.0616x; 1.0616x over previous
//
#include <hip/hip_runtime.h>
#include <cstdint>
#include <cstddef>

// ---------------------------------------------------------------------------
// MultiHeadAttention: x(4,2048,1024) @ W_qkv -> causal MHA (16 heads, d=64)
// -> @ W_out. fp32 in/out, fp16 MFMA internally (threshold 7.5e-2).
// R12 (271.2us): 4-wave QT=128 flash, proven 2-barrier schedule; Q-prescale,
//      cvt_pkrtz, setprio.
// R15 (263.2us): flash KT=128 (17 iters) + raw v_exp_f32.
// R16 (276.3us): cast-into-gemm_qkv fusion REGRESSED — fp32 A staging blew
//      L2 (FETCH 72.8->146MB, gemm_qkv 75->99us). REVERTED per trigger.
// R18: revert to R15 structure (cast kernel + fp16 A staging) + flash
//      XCD grouping: launch dim3(NHEADS, 8, BATCH) so XCD = h%8 — the 8
//      q-tile blocks sharing a head's K/V (512KB) co-locate on one XCD
//      (8 resident (b,h) pairs x 512KB = 4MB = L2). Was XCD = pr: 8-way
//      K/V replication across XCDs (flash FETCH 146MB vs ~48MB ideal).
//      Pure index permutation — no sync/traffic-structure change.
// ---------------------------------------------------------------------------

#define D_MODEL 1024
#define NHEADS  16
#define DHEAD   64
#define BATCH   4
#define SEQ     2048

typedef __attribute__((ext_vector_type(8))) _Float16 half8;
typedef __attribute__((ext_vector_type(4))) _Float16 half4;
typedef __attribute__((ext_vector_type(4))) float    f32x4;

__device__ __forceinline__ void async_copy16(const _Float16* g, _Float16* l) {
    __builtin_amdgcn_global_load_lds(
        (const __attribute__((address_space(1))) uint32_t*)g,
        (__attribute__((address_space(3))) uint32_t*)l, 16, 0, 0);
}

__device__ __forceinline__ float fast_exp2(float x) {
#if __has_builtin(__builtin_amdgcn_exp2f)
    return __builtin_amdgcn_exp2f(x);   // raw v_exp_f32; -inf -> 0
#else
    return exp2f(x);
#endif
}

// ---------------------------------------------------------------------------
// 1. elementwise cast fp32 -> fp16
// ---------------------------------------------------------------------------
__global__ void cast_f32_f16(const float* __restrict__ in,
                             _Float16* __restrict__ out) {
    int i = blockIdx.x * blockDim.x + threadIdx.x;
    float4 v = *(const float4*)(in + (size_t)i * 4);
    half4 o;
    o.x = (_Float16)v.x; o.y = (_Float16)v.y;
    o.z = (_Float16)v.z; o.w = (_Float16)v.w;
    *(half4*)(out + (size_t)i * 4) = o;
}

// ---------------------------------------------------------------------------
// 2. tiled transpose + cast: (R x C) fp32 -> (C x R) fp16
// ---------------------------------------------------------------------------
__global__ void transpose_cast(const float* __restrict__ in,
                               _Float16* __restrict__ out, int R, int C) {
    __shared__ float tile[32][33];
    int c0 = blockIdx.x * 32, r0 = blockIdx.y * 32;
    int tx = threadIdx.x, ty = threadIdx.y;
    #pragma unroll
    for (int i = 0; i < 32; i += 8)
        tile[ty + i][tx] = in[(size_t)(r0 + ty + i) * C + c0 + tx];
    __syncthreads();
    #pragma unroll
    for (int i = 0; i < 32; i += 8)
        out[(size_t)(c0 + ty + i) * R + r0 + tx] = (_Float16)tile[tx][ty + i];
}

// ---------------------------------------------------------------------------
// 3a. QKV GEMM: Xh[8192][1024] @ WqT[3072][1024]^T.
//     Cols < 2048 (Q,K) -> QK[8192][2048] row-major (direct stores).
//     Cols >= 2048 (V)  -> Vtg[(b*16+h)*64+d][2048] transposed, via an LDS
//     128x132 transpose so global stores are 16B-coalesced rows.
// ---------------------------------------------------------------------------
__global__ void gemm_qkv(const _Float16* __restrict__ A,
                         const _Float16* __restrict__ Bt,
                         _Float16* __restrict__ QK,
                         _Float16* __restrict__ Vtg) {
    __shared__ __attribute__((aligned(16))) _Float16 smem[128 * 132];
    _Float16* As = smem;
    _Float16* Bs = smem + 128 * 32;

    const int tid  = threadIdx.x;
    const int w    = tid >> 6, lane = tid & 63;
    const int l15  = lane & 15, quad = lane >> 4;
    const int wm   = w >> 1, wn = w & 1;
    const int row0 = blockIdx.y * 128, col0 = blockIdx.x * 128;
    const int K = 1024;

    f32x4 acc[4][4];
    #pragma unroll
    for (int i = 0; i < 4; i++)
        #pragma unroll
        for (int j = 0; j < 4; j++)
            acc[i][j] = (f32x4){0.f, 0.f, 0.f, 0.f};

    const int r0i = tid >> 2, c0i = tid & 3;
    const int r1i = (256 + tid) >> 2;

    for (int k0 = 0; k0 < K; k0 += 32) {
        __syncthreads();
        async_copy16(A  + (size_t)(row0 + r0i) * K + k0 + c0i * 8, &As[(w * 64) * 8]);
        async_copy16(A  + (size_t)(row0 + r1i) * K + k0 + c0i * 8, &As[(256 + w * 64) * 8]);
        async_copy16(Bt + (size_t)(col0 + r0i) * K + k0 + c0i * 8, &Bs[(w * 64) * 8]);
        async_copy16(Bt + (size_t)(col0 + r1i) * K + k0 + c0i * 8, &Bs[(256 + w * 64) * 8]);
        __syncthreads();

        half8 af[4], bfm[4];
        #pragma unroll
        for (int i = 0; i < 4; i++)
            af[i] = *(const half8*)&As[(wm * 64 + i * 16 + l15) * 32 + quad * 8];
        #pragma unroll
        for (int j = 0; j < 4; j++)
            bfm[j] = *(const half8*)&Bs[(wn * 64 + j * 16 + l15) * 32 + quad * 8];
        #pragma unroll
        for (int i = 0; i < 4; i++)
            #pragma unroll
            for (int j = 0; j < 4; j++)
                acc[i][j] = __builtin_amdgcn_mfma_f32_16x16x32_f16(
                    af[i], bfm[j], acc[i][j], 0, 0, 0);
    }

    if (blockIdx.x < 16) {  // Q,K region: row-major into QK (ld 2048)
        #pragma unroll
        for (int i = 0; i < 4; i++) {
            int row = row0 + wm * 64 + i * 16 + quad * 4;
            #pragma unroll
            for (int j = 0; j < 4; j++) {
                int col = col0 + wn * 64 + j * 16 + l15;
                #pragma unroll
                for (int r = 0; r < 4; r++)
                    QK[(size_t)(row + r) * 2048 + col] = (_Float16)acc[i][j][r];
            }
        }
    } else {
        // V region: transpose 128x128 tile through LDS, then coalesced rows.
        __syncthreads();
        #pragma unroll
        for (int i = 0; i < 4; i++) {
            int tl = wm * 64 + i * 16 + quad * 4;
            #pragma unroll
            for (int j = 0; j < 4; j++) {
                int vl = wn * 64 + j * 16 + l15;
                half4 pk;
                #pragma unroll
                for (int r = 0; r < 4; r++) pk[r] = (_Float16)acc[i][j][r];
                *(half4*)&smem[vl * 132 + tl] = pk;
            }
        }
        __syncthreads();
        const int bb = row0 >> 11, tb = row0 & 2047;
        const int rr0 = tid >> 4;
        const int cc  = (tid & 15) * 8;
        #pragma unroll
        for (int s = 0; s < 8; s++) {
            int vl = rr0 + s * 16;
            int vcol = (col0 - 2048) + vl;
            int hh = vcol >> 6, d = vcol & 63;
            *(half8*)&Vtg[((size_t)((bb * 16 + hh) * 64 + d)) * 2048 + tb + cc] =
                *(const half8*)&smem[vl * 132 + cc];
        }
    }
}

// ---------------------------------------------------------------------------
// 3b. output GEMM: Obuf[8192][1024] @ WoT[1024][1024]^T -> fp32 out
// ---------------------------------------------------------------------------
__global__ void gemm_out(const _Float16* __restrict__ A,
                         const _Float16* __restrict__ Bt,
                         float* __restrict__ Cf, int N, int K) {
    __shared__ __attribute__((aligned(16))) _Float16 As[128 * 32];
    __shared__ __attribute__((aligned(16))) _Float16 Bs[128 * 32];

    const int tid  = threadIdx.x;
    const int w    = tid >> 6, lane = tid & 63;
    const int l15  = lane & 15, quad = lane >> 4;
    const int wm   = w >> 1, wn = w & 1;
    const int row0 = blockIdx.y * 128, col0 = blockIdx.x * 128;

    f32x4 acc[4][4];
    #pragma unroll
    for (int i = 0; i < 4; i++)
        #pragma unroll
        for (int j = 0; j < 4; j++)
            acc[i][j] = (f32x4){0.f, 0.f, 0.f, 0.f};

    const int r0i = tid >> 2, c0i = tid & 3;
    const int r1i = (256 + tid) >> 2;

    for (int k0 = 0; k0 < K; k0 += 32) {
        __syncthreads();
        async_copy16(A  + (size_t)(row0 + r0i) * K + k0 + c0i * 8, &As[(w * 64) * 8]);
        async_copy16(A  + (size_t)(row0 + r1i) * K + k0 + c0i * 8, &As[(256 + w * 64) * 8]);
        async_copy16(Bt + (size_t)(col0 + r0i) * K + k0 + c0i * 8, &Bs[(w * 64) * 8]);
        async_copy16(Bt + (size_t)(col0 + r1i) * K + k0 + c0i * 8, &Bs[(256 + w * 64) * 8]);
        __syncthreads();

        half8 af[4], bfm[4];
        #pragma unroll
        for (int i = 0; i < 4; i++)
            af[i] = *(const half8*)&As[(wm * 64 + i * 16 + l15) * 32 + quad * 8];
        #pragma unroll
        for (int j = 0; j < 4; j++)
            bfm[j] = *(const half8*)&Bs[(wn * 64 + j * 16 + l15) * 32 + quad * 8];
        #pragma unroll
        for (int i = 0; i < 4; i++)
            #pragma unroll
            for (int j = 0; j < 4; j++)
                acc[i][j] = __builtin_amdgcn_mfma_f32_16x16x32_f16(
                    af[i], bfm[j], acc[i][j], 0, 0, 0);
    }

    #pragma unroll
    for (int i = 0; i < 4; i++) {
        int row = row0 + wm * 64 + i * 16 + quad * 4;
        #pragma unroll
        for (int j = 0; j < 4; j++) {
            int col = col0 + wn * 64 + j * 16 + l15;
            #pragma unroll
            for (int r = 0; r < 4; r++)
                Cf[(size_t)(row + r) * N + col] = acc[i][j][r];
        }
    }
}

// ---------------------------------------------------------------------------
// 4. Flash attention (causal). QT=128 per block, 4 waves x 256 thr,
//    wave = 32 q rows (2 groups), KT=128 (17 iters). Pairing (pr, 15-pr);
//    grid dim3(NHEADS, 8, BATCH): h = blockIdx.x so XCD = h%8 — all 8
//    q-tile blocks of a head co-locate on one XCD (K/V L2-resident).
//    Proven sync template per iter: {bar; ds_write K/V tile; bar;
//    reg-prefetch next tile; compute}. K tile 128x64 (rows=kv), V tile
//    64x128 (rows=d). Q pre-scaled by log2(e)/8; raw v_exp_f32;
//    cvt_pkrtz P-packing; setprio around MFMA. S^T layout (A=K, B=Q).
//    QK processed in two nt-halves to cap st liveness.
// ---------------------------------------------------------------------------
#define PREFETCH(t)                                                          \
    do {                                                                     \
        const _Float16* kp_ = kb + (size_t)((t) * 128 + srow) * 2048 + sc;   \
        kr0 = *(const half8*)kp_;                                            \
        kr1 = *(const half8*)(kp_ + (size_t)32 * 2048);                      \
        kr2 = *(const half8*)(kp_ + (size_t)64 * 2048);                      \
        kr3 = *(const half8*)(kp_ + (size_t)96 * 2048);                      \
        const _Float16* vp_ = vb + (size_t)srow * 2048 + (t) * 128 + sc;     \
        vr0 = *(const half8*)vp_;                                            \
        vr1 = *(const half8*)(vp_ + 64);                                     \
        vr2 = *(const half8*)(vp_ + (size_t)32 * 2048);                      \
        vr3 = *(const half8*)(vp_ + (size_t)32 * 2048 + 64);                 \
    } while (0)

__global__ __launch_bounds__(256, 2) void flash_attn(
        const _Float16* __restrict__ qk, const _Float16* __restrict__ vt,
        _Float16* __restrict__ obuf) {
    const int h = blockIdx.x, pr = blockIdx.y, b = blockIdx.z;  // XCD = h%8
    const int tid = threadIdx.x;
    const int w = tid >> 6, lane = tid & 63;
    const int l15 = lane & 15, quad = lane >> 4;

    __shared__ __attribute__((aligned(16))) _Float16 Ks[128 * 72];   // rows=kv, cols=d
    __shared__ __attribute__((aligned(16))) _Float16 Vs[64 * 136];   // rows=d,  cols=kv
    __shared__ __attribute__((aligned(16))) _Float16 Pl[4][32 * 136];

    const _Float16* kb = qk + (size_t)b * SEQ * 2048 + D_MODEL + h * 64;
    const _Float16* vb = vt + (size_t)(b * 16 + h) * 64 * 2048;

    const int srow = tid >> 3;        // staging row 0..31 (+32/64/96)
    const int sc   = (tid & 7) * 8;   // 16B chunk within 64-elem row

    const _Float16 QSCL = (_Float16)0.18033688f;  // log2(e)/sqrt(64)

    #pragma unroll 1
    for (int phase = 0; phase < 2; ++phase) {
        const int tq = phase ? (15 - pr) : pr;
        const int q0 = tq * 128;
        const int n_iter = tq + 1;          // KT=128 tiles

        // Q as MFMA B-frag: B[n=q][k=d], 2 groups x 2 k-frags, pre-scaled
        half8 qf[2][2];
        #pragma unroll
        for (int g = 0; g < 2; g++) {
            const _Float16* qp = qk
                + ((size_t)(b * SEQ + q0 + w * 32 + g * 16 + l15)) * 2048
                + h * DHEAD + quad * 8;
            qf[g][0] = *(const half8*)qp;
            qf[g][1] = *(const half8*)(qp + 32);
            #pragma unroll
            for (int j = 0; j < 8; j++) {
                qf[g][0][j] *= QSCL;
                qf[g][1][j] *= QSCL;
            }
        }

        f32x4 o[2][4];
        float l_acc[2] = {0.f, 0.f};
        #pragma unroll
        for (int g = 0; g < 2; g++)
            #pragma unroll
            for (int d = 0; d < 4; d++) o[g][d] = (f32x4){0.f, 0.f, 0.f, 0.f};

        half8 kr0, kr1, kr2, kr3, vr0, vr1, vr2, vr3;
        PREFETCH(0);   // tile 0 into regs

        #pragma unroll 1
        for (int it = 0; it < n_iter; ++it) {
            __syncthreads();
            *(half8*)&Ks[(srow      ) * 72 + sc] = kr0;
            *(half8*)&Ks[(srow + 32 ) * 72 + sc] = kr1;
            *(half8*)&Ks[(srow + 64 ) * 72 + sc] = kr2;
            *(half8*)&Ks[(srow + 96 ) * 72 + sc] = kr3;
            *(half8*)&Vs[srow * 136 + sc]             = vr0;
            *(half8*)&Vs[srow * 136 + sc + 64]        = vr1;
            *(half8*)&Vs[(srow + 32) * 136 + sc]      = vr2;
            *(half8*)&Vs[(srow + 32) * 136 + sc + 64] = vr3;
            __syncthreads();

            if (it + 1 < n_iter) PREFETCH(it + 1);

            // S^T = K Q^T, two nt-halves of 4 (kv 0..63, 64..127); K frags
            // read once per half, reused across both q-groups.
            #pragma unroll
            for (int hh = 0; hh < 2; hh++) {
                f32x4 st[2][4];
                __builtin_amdgcn_s_setprio(1);
                #pragma unroll
                for (int n4 = 0; n4 < 4; n4++) {
                    const int nt = hh * 4 + n4;
                    half8 ka0 = *(const half8*)&Ks[(nt * 16 + l15) * 72 + quad * 8];
                    half8 ka1 = *(const half8*)&Ks[(nt * 16 + l15) * 72 + 32 + quad * 8];
                    #pragma unroll
                    for (int g = 0; g < 2; g++) {
                        f32x4 acc = (f32x4){0.f, 0.f, 0.f, 0.f};
                        acc = __builtin_amdgcn_mfma_f32_16x16x32_f16(ka0, qf[g][0], acc, 0, 0, 0);
                        acc = __builtin_amdgcn_mfma_f32_16x16x32_f16(ka1, qf[g][1], acc, 0, 0, 0);
                        st[g][n4] = acc;
                    }
                }
                __builtin_amdgcn_s_setprio(0);

                // causal mask (partial tiles only) + exp2 + P -> LDS (b64).
                // Dead groups fall into the mask path and store zeros.
                #pragma unroll
                for (int g = 0; g < 2; g++) {
                    const int c0 = __builtin_amdgcn_readfirstlane(
                        q0 + w * 32 + g * 16 - 128 * it);
                    if (c0 < 127) {
                        #pragma unroll
                        for (int n4 = 0; n4 < 4; n4++)
                            #pragma unroll
                            for (int r = 0; r < 4; r++)
                                if ((hh * 4 + n4) * 16 + quad * 4 + r - l15 > c0)
                                    st[g][n4][r] = -INFINITY;
                    }
                    #pragma unroll
                    for (int n4 = 0; n4 < 4; n4++) {
                        const int nt = hh * 4 + n4;
                        float p0 = fast_exp2(st[g][n4][0]);
                        float p1 = fast_exp2(st[g][n4][1]);
                        float p2 = fast_exp2(st[g][n4][2]);
                        float p3 = fast_exp2(st[g][n4][3]);
                        l_acc[g] += (p0 + p1) + (p2 + p3);
                        auto lo = __builtin_amdgcn_cvt_pkrtz(p0, p1);
                        auto hi = __builtin_amdgcn_cvt_pkrtz(p2, p3);
                        half4 pk;
                        pk[0] = (_Float16)lo[0]; pk[1] = (_Float16)lo[1];
                        pk[2] = (_Float16)hi[0]; pk[3] = (_Float16)hi[1];
                        *(half4*)&Pl[w][(g * 16 + l15) * 136 + nt * 16 + quad * 4] = pk;
                    }
                }
            }
            asm volatile("s_waitcnt lgkmcnt(0)" ::: "memory");  // same-wave RAW

            // O += P V : V frags read once, reused across both q-groups.
            __builtin_amdgcn_s_setprio(1);
            #pragma unroll
            for (int kf = 0; kf < 4; kf++) {
                half8 pf0 = *(const half8*)&Pl[w][l15 * 136 + kf * 32 + quad * 8];
                half8 pf1 = *(const half8*)&Pl[w][(16 + l15) * 136 + kf * 32 + quad * 8];
                #pragma unroll
                for (int dt = 0; dt < 4; dt++) {
                    half8 vf = *(const half8*)&Vs[(dt * 16 + l15) * 136 + kf * 32 + quad * 8];
                    o[0][dt] = __builtin_amdgcn_mfma_f32_16x16x32_f16(pf0, vf, o[0][dt], 0, 0, 0);
                    o[1][dt] = __builtin_amdgcn_mfma_f32_16x16x32_f16(pf1, vf, o[1][dt], 0, 0, 0);
                }
            }
            __builtin_amdgcn_s_setprio(0);
        }

        // epilogue per group: reduce l over quads, divide, store fp16
        #pragma unroll
        for (int g = 0; g < 2; g++) {
            float l = l_acc[g];
            l += __shfl_xor(l, 16);
            l += __shfl_xor(l, 32);   // every lane: L[q = l15]
            float linv[4];
            #pragma unroll
            for (int r = 0; r < 4; r++)
                linv[r] = 1.0f / __shfl(l, quad * 4 + r, 16);

            _Float16* ob = obuf
                + ((size_t)(b * SEQ + q0 + w * 32 + g * 16 + quad * 4)) * D_MODEL
                + h * DHEAD;
            #pragma unroll
            for (int r = 0; r < 4; r++) {
                #pragma unroll
                for (int dt = 0; dt < 4; dt++)
                    ob[(size_t)r * D_MODEL + dt * 16 + l15] =
                        (_Float16)(o[g][dt][r] * linv[r]);
            }
        }
        __syncthreads();  // protect Ks/Vs before next phase's first stage
    }
}

// ---------------------------------------------------------------------------
// launch
// ---------------------------------------------------------------------------
extern "C" void kernel_launch(void* const* d_in, const int* in_sizes, int n_in,
                              void* d_out, int out_size, void* d_ws, size_t ws_size,
                              hipStream_t stream) {
    const float* x    = (const float*)d_in[0];
    const float* Wqkv = (const float*)d_in[1];
    const float* Wout = (const float*)d_in[2];
    float* out = (float*)d_out;

    char* ws = (char*)d_ws;
    _Float16* Xh   = (_Float16*)(ws);                          // 16 MB
    _Float16* WqT  = (_Float16*)(ws + ((size_t)16 << 20));     //  6 MB
    _Float16* WoT  = (_Float16*)(ws + ((size_t)23 << 20));     //  2 MB
    _Float16* QKb  = (_Float16*)(ws + ((size_t)26 << 20));     // 32 MB
    _Float16* Vtg  = (_Float16*)(ws + ((size_t)58 << 20));     // 16 MB
    _Float16* Obuf = (_Float16*)(ws + ((size_t)74 << 20));     // 16 MB -> 90 MB

    cast_f32_f16<<<8192, 256, 0, stream>>>(x, Xh);
    transpose_cast<<<dim3(96, 32), dim3(32, 8), 0, stream>>>(Wqkv, WqT, 1024, 3072);
    transpose_cast<<<dim3(32, 32), dim3(32, 8), 0, stream>>>(Wout, WoT, 1024, 1024);
    gemm_qkv<<<dim3(24, 64), 256, 0, stream>>>(Xh, WqT, QKb, Vtg);
    flash_attn<<<dim3(NHEADS, 8, BATCH), 256, 0, stream>>>(QKb, Vtg, Obuf);
    gemm_out<<<dim3(8, 64), 256, 0, stream>>>(Obuf, WoT, out, 1024, 1024);
}

// Round 15
// 258.485 us; speedup vs baseline: 1.0690x; 1.0070x over previous
//
#include <hip/hip_runtime.h>
#include <cstdint>
#include <cstddef>

// ---------------------------------------------------------------------------
// MultiHeadAttention: x(4,2048,1024) @ W_qkv -> causal MHA (16 heads, d=64)
// -> @ W_out. fp32 in/out, fp16 MFMA internally (threshold 7.5e-2).
// R12 (271.2us): 4-wave QT=128 flash, proven 2-barrier schedule; Q-prescale,
//      cvt_pkrtz, setprio.
// R15 (263.2us): flash KT=128 (17 iters) + raw v_exp_f32.
// R16 (276.3us): cast-fusion REGRESSED (fp32 A blew L2). REVERTED.
// R18 (260.3us): flash XCD head-grouping (dim3(NHEADS,8,BATCH), XCD=h%8);
//      flash now <73.8us; top kernel gemm_qkv 74.5us (692 TF, Mfma 28 /
//      VALU 13.5 / HBM 21 — nothing saturated; cost = 2 barriers + vmcnt
//      drain per K-step x 32 steps).
// R19: gemm_qkv BK 32->64 — halve lockstep events (16 iters, 32 MFMA per
//      drain), same {bar; stage; bar; compute} template, fp16 staging.
//      64-col rows (128B stride) would 16-way-conflict on frag reads, so
//      rule-21 XOR swizzle (proven correct in R16): linear gll dest +
//      source chunk ^ (row&7) + same XOR on LDS read -> 2-way (free).
//      LDS 32KB fits existing smem; V-transpose epilogue untouched.
// ---------------------------------------------------------------------------

#define D_MODEL 1024
#define NHEADS  16
#define DHEAD   64
#define BATCH   4
#define SEQ     2048

typedef __attribute__((ext_vector_type(8))) _Float16 half8;
typedef __attribute__((ext_vector_type(4))) _Float16 half4;
typedef __attribute__((ext_vector_type(4))) float    f32x4;

__device__ __forceinline__ void async_copy16(const _Float16* g, _Float16* l) {
    __builtin_amdgcn_global_load_lds(
        (const __attribute__((address_space(1))) uint32_t*)g,
        (__attribute__((address_space(3))) uint32_t*)l, 16, 0, 0);
}

__device__ __forceinline__ float fast_exp2(float x) {
#if __has_builtin(__builtin_amdgcn_exp2f)
    return __builtin_amdgcn_exp2f(x);   // raw v_exp_f32; -inf -> 0
#else
    return exp2f(x);
#endif
}

// ---------------------------------------------------------------------------
// 1. elementwise cast fp32 -> fp16
// ---------------------------------------------------------------------------
__global__ void cast_f32_f16(const float* __restrict__ in,
                             _Float16* __restrict__ out) {
    int i = blockIdx.x * blockDim.x + threadIdx.x;
    float4 v = *(const float4*)(in + (size_t)i * 4);
    half4 o;
    o.x = (_Float16)v.x; o.y = (_Float16)v.y;
    o.z = (_Float16)v.z; o.w = (_Float16)v.w;
    *(half4*)(out + (size_t)i * 4) = o;
}

// ---------------------------------------------------------------------------
// 2. tiled transpose + cast: (R x C) fp32 -> (C x R) fp16
// ---------------------------------------------------------------------------
__global__ void transpose_cast(const float* __restrict__ in,
                               _Float16* __restrict__ out, int R, int C) {
    __shared__ float tile[32][33];
    int c0 = blockIdx.x * 32, r0 = blockIdx.y * 32;
    int tx = threadIdx.x, ty = threadIdx.y;
    #pragma unroll
    for (int i = 0; i < 32; i += 8)
        tile[ty + i][tx] = in[(size_t)(r0 + ty + i) * C + c0 + tx];
    __syncthreads();
    #pragma unroll
    for (int i = 0; i < 32; i += 8)
        out[(size_t)(c0 + ty + i) * R + r0 + tx] = (_Float16)tile[tx][ty + i];
}

// ---------------------------------------------------------------------------
// 3a. QKV GEMM: Xh[8192][1024] @ WqT[3072][1024]^T.  BK=64, 16 K-iters.
//     A/B tiles 128x64 fp16, XOR-chunk-swizzled (LDS[r][c]=G[r][c^(r&7)]).
//     Cols < 2048 (Q,K) -> QK[8192][2048] row-major (direct stores).
//     Cols >= 2048 (V)  -> Vtg[(b*16+h)*64+d][2048] transposed, via an LDS
//     128x132 transpose so global stores are 16B-coalesced rows.
// ---------------------------------------------------------------------------
__global__ void gemm_qkv(const _Float16* __restrict__ A,
                         const _Float16* __restrict__ Bt,
                         _Float16* __restrict__ QK,
                         _Float16* __restrict__ Vtg) {
    __shared__ __attribute__((aligned(16))) _Float16 smem[128 * 132];
    _Float16* As = smem;            // 128 x 64, chunk-swizzled (16KB)
    _Float16* Bs = smem + 8192;     // 128 x 64, chunk-swizzled (16KB)

    const int tid  = threadIdx.x;
    const int w    = tid >> 6, lane = tid & 63;
    const int l15  = lane & 15, quad = lane >> 4;
    const int wm   = w >> 1, wn = w & 1;
    const int row0 = blockIdx.y * 128, col0 = blockIdx.x * 128;
    const int K = 1024;

    f32x4 acc[4][4];
    #pragma unroll
    for (int i = 0; i < 4; i++)
        #pragma unroll
        for (int j = 0; j < 4; j++)
            acc[i][j] = (f32x4){0.f, 0.f, 0.f, 0.f};

    const int lr  = lane >> 3;        // row 0..7 within wave's 8-row band
    const int src = (lane & 7) ^ lr;  // pre-swizzled source chunk (8 halfs)

    for (int k0 = 0; k0 < K; k0 += 64) {
        __syncthreads();
        #pragma unroll
        for (int q = 0; q < 4; q++) {
            async_copy16(A  + (size_t)(row0 + q * 32 + w * 8 + lr) * K + k0 + src * 8,
                         &As[(q * 32 + w * 8) * 64]);
            async_copy16(Bt + (size_t)(col0 + q * 32 + w * 8 + lr) * K + k0 + src * 8,
                         &Bs[(q * 32 + w * 8) * 64]);
        }
        __syncthreads();

        half8 af[2][4], bfm[2][4];
        #pragma unroll
        for (int i = 0; i < 4; i++) {
            const int ar = wm * 64 + i * 16 + l15;
            const int rs = ar & 7;
            #pragma unroll
            for (int kk = 0; kk < 2; kk++)
                af[kk][i] = *(const half8*)&As[ar * 64 + ((kk * 4 + quad) ^ rs) * 8];
        }
        #pragma unroll
        for (int j = 0; j < 4; j++) {
            const int br = wn * 64 + j * 16 + l15;
            const int rs = br & 7;
            #pragma unroll
            for (int kk = 0; kk < 2; kk++)
                bfm[kk][j] = *(const half8*)&Bs[br * 64 + ((kk * 4 + quad) ^ rs) * 8];
        }
        #pragma unroll
        for (int kk = 0; kk < 2; kk++)
            #pragma unroll
            for (int i = 0; i < 4; i++)
                #pragma unroll
                for (int j = 0; j < 4; j++)
                    acc[i][j] = __builtin_amdgcn_mfma_f32_16x16x32_f16(
                        af[kk][i], bfm[kk][j], acc[i][j], 0, 0, 0);
    }

    if (blockIdx.x < 16) {  // Q,K region: row-major into QK (ld 2048)
        #pragma unroll
        for (int i = 0; i < 4; i++) {
            int row = row0 + wm * 64 + i * 16 + quad * 4;
            #pragma unroll
            for (int j = 0; j < 4; j++) {
                int col = col0 + wn * 64 + j * 16 + l15;
                #pragma unroll
                for (int r = 0; r < 4; r++)
                    QK[(size_t)(row + r) * 2048 + col] = (_Float16)acc[i][j][r];
            }
        }
    } else {
        // V region: transpose 128x128 tile through LDS, then coalesced rows.
        __syncthreads();
        #pragma unroll
        for (int i = 0; i < 4; i++) {
            int tl = wm * 64 + i * 16 + quad * 4;
            #pragma unroll
            for (int j = 0; j < 4; j++) {
                int vl = wn * 64 + j * 16 + l15;
                half4 pk;
                #pragma unroll
                for (int r = 0; r < 4; r++) pk[r] = (_Float16)acc[i][j][r];
                *(half4*)&smem[vl * 132 + tl] = pk;
            }
        }
        __syncthreads();
        const int bb = row0 >> 11, tb = row0 & 2047;
        const int rr0 = tid >> 4;
        const int cc  = (tid & 15) * 8;
        #pragma unroll
        for (int s = 0; s < 8; s++) {
            int vl = rr0 + s * 16;
            int vcol = (col0 - 2048) + vl;
            int hh = vcol >> 6, d = vcol & 63;
            *(half8*)&Vtg[((size_t)((bb * 16 + hh) * 64 + d)) * 2048 + tb + cc] =
                *(const half8*)&smem[vl * 132 + cc];
        }
    }
}

// ---------------------------------------------------------------------------
// 3b. output GEMM: Obuf[8192][1024] @ WoT[1024][1024]^T -> fp32 out
// ---------------------------------------------------------------------------
__global__ void gemm_out(const _Float16* __restrict__ A,
                         const _Float16* __restrict__ Bt,
                         float* __restrict__ Cf, int N, int K) {
    __shared__ __attribute__((aligned(16))) _Float16 As[128 * 32];
    __shared__ __attribute__((aligned(16))) _Float16 Bs[128 * 32];

    const int tid  = threadIdx.x;
    const int w    = tid >> 6, lane = tid & 63;
    const int l15  = lane & 15, quad = lane >> 4;
    const int wm   = w >> 1, wn = w & 1;
    const int row0 = blockIdx.y * 128, col0 = blockIdx.x * 128;

    f32x4 acc[4][4];
    #pragma unroll
    for (int i = 0; i < 4; i++)
        #pragma unroll
        for (int j = 0; j < 4; j++)
            acc[i][j] = (f32x4){0.f, 0.f, 0.f, 0.f};

    const int r0i = tid >> 2, c0i = tid & 3;
    const int r1i = (256 + tid) >> 2;

    for (int k0 = 0; k0 < K; k0 += 32) {
        __syncthreads();
        async_copy16(A  + (size_t)(row0 + r0i) * K + k0 + c0i * 8, &As[(w * 64) * 8]);
        async_copy16(A  + (size_t)(row0 + r1i) * K + k0 + c0i * 8, &As[(256 + w * 64) * 8]);
        async_copy16(Bt + (size_t)(col0 + r0i) * K + k0 + c0i * 8, &Bs[(w * 64) * 8]);
        async_copy16(Bt + (size_t)(col0 + r1i) * K + k0 + c0i * 8, &Bs[(256 + w * 64) * 8]);
        __syncthreads();

        half8 af[4], bfm[4];
        #pragma unroll
        for (int i = 0; i < 4; i++)
            af[i] = *(const half8*)&As[(wm * 64 + i * 16 + l15) * 32 + quad * 8];
        #pragma unroll
        for (int j = 0; j < 4; j++)
            bfm[j] = *(const half8*)&Bs[(wn * 64 + j * 16 + l15) * 32 + quad * 8];
        #pragma unroll
        for (int i = 0; i < 4; i++)
            #pragma unroll
            for (int j = 0; j < 4; j++)
                acc[i][j] = __builtin_amdgcn_mfma_f32_16x16x32_f16(
                    af[i], bfm[j], acc[i][j], 0, 0, 0);
    }

    #pragma unroll
    for (int i = 0; i < 4; i++) {
        int row = row0 + wm * 64 + i * 16 + quad * 4;
        #pragma unroll
        for (int j = 0; j < 4; j++) {
            int col = col0 + wn * 64 + j * 16 + l15;
            #pragma unroll
            for (int r = 0; r < 4; r++)
                Cf[(size_t)(row + r) * N + col] = acc[i][j][r];
        }
    }
}

// ---------------------------------------------------------------------------
// 4. Flash attention (causal). QT=128 per block, 4 waves x 256 thr,
//    wave = 32 q rows (2 groups), KT=128 (17 iters). Pairing (pr, 15-pr);
//    grid dim3(NHEADS, 8, BATCH): h = blockIdx.x so XCD = h%8 — all 8
//    q-tile blocks of a head co-locate on one XCD (K/V L2-resident).
//    Proven sync template per iter: {bar; ds_write K/V tile; bar;
//    reg-prefetch next tile; compute}. K tile 128x64 (rows=kv), V tile
//    64x128 (rows=d). Q pre-scaled by log2(e)/8; raw v_exp_f32;
//    cvt_pkrtz P-packing; setprio around MFMA. S^T layout (A=K, B=Q).
//    QK processed in two nt-halves to cap st liveness.
// ---------------------------------------------------------------------------
#define PREFETCH(t)                                                          \
    do {                                                                     \
        const _Float16* kp_ = kb + (size_t)((t) * 128 + srow) * 2048 + sc;   \
        kr0 = *(const half8*)kp_;                                            \
        kr1 = *(const half8*)(kp_ + (size_t)32 * 2048);                      \
        kr2 = *(const half8*)(kp_ + (size_t)64 * 2048);                      \
        kr3 = *(const half8*)(kp_ + (size_t)96 * 2048);                      \
        const _Float16* vp_ = vb + (size_t)srow * 2048 + (t) * 128 + sc;     \
        vr0 = *(const half8*)vp_;                                            \
        vr1 = *(const half8*)(vp_ + 64);                                     \
        vr2 = *(const half8*)(vp_ + (size_t)32 * 2048);                      \
        vr3 = *(const half8*)(vp_ + (size_t)32 * 2048 + 64);                 \
    } while (0)

__global__ __launch_bounds__(256, 2) void flash_attn(
        const _Float16* __restrict__ qk, const _Float16* __restrict__ vt,
        _Float16* __restrict__ obuf) {
    const int h = blockIdx.x, pr = blockIdx.y, b = blockIdx.z;  // XCD = h%8
    const int tid = threadIdx.x;
    const int w = tid >> 6, lane = tid & 63;
    const int l15 = lane & 15, quad = lane >> 4;

    __shared__ __attribute__((aligned(16))) _Float16 Ks[128 * 72];   // rows=kv, cols=d
    __shared__ __attribute__((aligned(16))) _Float16 Vs[64 * 136];   // rows=d,  cols=kv
    __shared__ __attribute__((aligned(16))) _Float16 Pl[4][32 * 136];

    const _Float16* kb = qk + (size_t)b * SEQ * 2048 + D_MODEL + h * 64;
    const _Float16* vb = vt + (size_t)(b * 16 + h) * 64 * 2048;

    const int srow = tid >> 3;        // staging row 0..31 (+32/64/96)
    const int sc   = (tid & 7) * 8;   // 16B chunk within 64-elem row

    const _Float16 QSCL = (_Float16)0.18033688f;  // log2(e)/sqrt(64)

    #pragma unroll 1
    for (int phase = 0; phase < 2; ++phase) {
        const int tq = phase ? (15 - pr) : pr;
        const int q0 = tq * 128;
        const int n_iter = tq + 1;          // KT=128 tiles

        // Q as MFMA B-frag: B[n=q][k=d], 2 groups x 2 k-frags, pre-scaled
        half8 qf[2][2];
        #pragma unroll
        for (int g = 0; g < 2; g++) {
            const _Float16* qp = qk
                + ((size_t)(b * SEQ + q0 + w * 32 + g * 16 + l15)) * 2048
                + h * DHEAD + quad * 8;
            qf[g][0] = *(const half8*)qp;
            qf[g][1] = *(const half8*)(qp + 32);
            #pragma unroll
            for (int j = 0; j < 8; j++) {
                qf[g][0][j] *= QSCL;
                qf[g][1][j] *= QSCL;
            }
        }

        f32x4 o[2][4];
        float l_acc[2] = {0.f, 0.f};
        #pragma unroll
        for (int g = 0; g < 2; g++)
            #pragma unroll
            for (int d = 0; d < 4; d++) o[g][d] = (f32x4){0.f, 0.f, 0.f, 0.f};

        half8 kr0, kr1, kr2, kr3, vr0, vr1, vr2, vr3;
        PREFETCH(0);   // tile 0 into regs

        #pragma unroll 1
        for (int it = 0; it < n_iter; ++it) {
            __syncthreads();
            *(half8*)&Ks[(srow      ) * 72 + sc] = kr0;
            *(half8*)&Ks[(srow + 32 ) * 72 + sc] = kr1;
            *(half8*)&Ks[(srow + 64 ) * 72 + sc] = kr2;
            *(half8*)&Ks[(srow + 96 ) * 72 + sc] = kr3;
            *(half8*)&Vs[srow * 136 + sc]             = vr0;
            *(half8*)&Vs[srow * 136 + sc + 64]        = vr1;
            *(half8*)&Vs[(srow + 32) * 136 + sc]      = vr2;
            *(half8*)&Vs[(srow + 32) * 136 + sc + 64] = vr3;
            __syncthreads();

            if (it + 1 < n_iter) PREFETCH(it + 1);

            // S^T = K Q^T, two nt-halves of 4 (kv 0..63, 64..127); K frags
            // read once per half, reused across both q-groups.
            #pragma unroll
            for (int hh = 0; hh < 2; hh++) {
                f32x4 st[2][4];
                __builtin_amdgcn_s_setprio(1);
                #pragma unroll
                for (int n4 = 0; n4 < 4; n4++) {
                    const int nt = hh * 4 + n4;
                    half8 ka0 = *(const half8*)&Ks[(nt * 16 + l15) * 72 + quad * 8];
                    half8 ka1 = *(const half8*)&Ks[(nt * 16 + l15) * 72 + 32 + quad * 8];
                    #pragma unroll
                    for (int g = 0; g < 2; g++) {
                        f32x4 acc = (f32x4){0.f, 0.f, 0.f, 0.f};
                        acc = __builtin_amdgcn_mfma_f32_16x16x32_f16(ka0, qf[g][0], acc, 0, 0, 0);
                        acc = __builtin_amdgcn_mfma_f32_16x16x32_f16(ka1, qf[g][1], acc, 0, 0, 0);
                        st[g][n4] = acc;
                    }
                }
                __builtin_amdgcn_s_setprio(0);

                // causal mask (partial tiles only) + exp2 + P -> LDS (b64).
                // Dead groups fall into the mask path and store zeros.
                #pragma unroll
                for (int g = 0; g < 2; g++) {
                    const int c0 = __builtin_amdgcn_readfirstlane(
                        q0 + w * 32 + g * 16 - 128 * it);
                    if (c0 < 127) {
                        #pragma unroll
                        for (int n4 = 0; n4 < 4; n4++)
                            #pragma unroll
                            for (int r = 0; r < 4; r++)
                                if ((hh * 4 + n4) * 16 + quad * 4 + r - l15 > c0)
                                    st[g][n4][r] = -INFINITY;
                    }
                    #pragma unroll
                    for (int n4 = 0; n4 < 4; n4++) {
                        const int nt = hh * 4 + n4;
                        float p0 = fast_exp2(st[g][n4][0]);
                        float p1 = fast_exp2(st[g][n4][1]);
                        float p2 = fast_exp2(st[g][n4][2]);
                        float p3 = fast_exp2(st[g][n4][3]);
                        l_acc[g] += (p0 + p1) + (p2 + p3);
                        auto lo = __builtin_amdgcn_cvt_pkrtz(p0, p1);
                        auto hi = __builtin_amdgcn_cvt_pkrtz(p2, p3);
                        half4 pk;
                        pk[0] = (_Float16)lo[0]; pk[1] = (_Float16)lo[1];
                        pk[2] = (_Float16)hi[0]; pk[3] = (_Float16)hi[1];
                        *(half4*)&Pl[w][(g * 16 + l15) * 136 + nt * 16 + quad * 4] = pk;
                    }
                }
            }
            asm volatile("s_waitcnt lgkmcnt(0)" ::: "memory");  // same-wave RAW

            // O += P V : V frags read once, reused across both q-groups.
            __builtin_amdgcn_s_setprio(1);
            #pragma unroll
            for (int kf = 0; kf < 4; kf++) {
                half8 pf0 = *(const half8*)&Pl[w][l15 * 136 + kf * 32 + quad * 8];
                half8 pf1 = *(const half8*)&Pl[w][(16 + l15) * 136 + kf * 32 + quad * 8];
                #pragma unroll
                for (int dt = 0; dt < 4; dt++) {
                    half8 vf = *(const half8*)&Vs[(dt * 16 + l15) * 136 + kf * 32 + quad * 8];
                    o[0][dt] = __builtin_amdgcn_mfma_f32_16x16x32_f16(pf0, vf, o[0][dt], 0, 0, 0);
                    o[1][dt] = __builtin_amdgcn_mfma_f32_16x16x32_f16(pf1, vf, o[1][dt], 0, 0, 0);
                }
            }
            __builtin_amdgcn_s_setprio(0);
        }

        // epilogue per group: reduce l over quads, divide, store fp16
        #pragma unroll
        for (int g = 0; g < 2; g++) {
            float l = l_acc[g];
            l += __shfl_xor(l, 16);
            l += __shfl_xor(l, 32);   // every lane: L[q = l15]
            float linv[4];
            #pragma unroll
            for (int r = 0; r < 4; r++)
                linv[r] = 1.0f / __shfl(l, quad * 4 + r, 16);

            _Float16* ob = obuf
                + ((size_t)(b * SEQ + q0 + w * 32 + g * 16 + quad * 4)) * D_MODEL
                + h * DHEAD;
            #pragma unroll
            for (int r = 0; r < 4; r++) {
                #pragma unroll
                for (int dt = 0; dt < 4; dt++)
                    ob[(size_t)r * D_MODEL + dt * 16 + l15] =
                        (_Float16)(o[g][dt][r] * linv[r]);
            }
        }
        __syncthreads();  // protect Ks/Vs before next phase's first stage
    }
}

// ---------------------------------------------------------------------------
// launch
// ---------------------------------------------------------------------------
extern "C" void kernel_launch(void* const* d_in, const int* in_sizes, int n_in,
                              void* d_out, int out_size, void* d_ws, size_t ws_size,
                              hipStream_t stream) {
    const float* x    = (const float*)d_in[0];
    const float* Wqkv = (const float*)d_in[1];
    const float* Wout = (const float*)d_in[2];
    float* out = (float*)d_out;

    char* ws = (char*)d_ws;
    _Float16* Xh   = (_Float16*)(ws);                          // 16 MB
    _Float16* WqT  = (_Float16*)(ws + ((size_t)16 << 20));     //  6 MB
    _Float16* WoT  = (_Float16*)(ws + ((size_t)23 << 20));     //  2 MB
    _Float16* QKb  = (_Float16*)(ws + ((size_t)26 << 20));     // 32 MB
    _Float16* Vtg  = (_Float16*)(ws + ((size_t)58 << 20));     // 16 MB
    _Float16* Obuf = (_Float16*)(ws + ((size_t)74 << 20));     // 16 MB -> 90 MB

    cast_f32_f16<<<8192, 256, 0, stream>>>(x, Xh);
    transpose_cast<<<dim3(96, 32), dim3(32, 8), 0, stream>>>(Wqkv, WqT, 1024, 3072);
    transpose_cast<<<dim3(32, 32), dim3(32, 8), 0, stream>>>(Wout, WoT, 1024, 1024);
    gemm_qkv<<<dim3(24, 64), 256, 0, stream>>>(Xh, WqT, QKb, Vtg);
    flash_attn<<<dim3(NHEADS, 8, BATCH), 256, 0, stream>>>(QKb, Vtg, Obuf);
    gemm_out<<<dim3(8, 64), 256, 0, stream>>>(Obuf, WoT, out, 1024, 1024);
}

// Round 21
// 247.278 us; speedup vs baseline: 1.1174x; 1.0453x over previous
//
#include <hip/hip_runtime.h>
#include <cstdint>
#include <cstddef>

// ---------------------------------------------------------------------------
// MultiHeadAttention: x(4,2048,1024) @ W_qkv -> causal MHA (16 heads, d=64)
// -> @ W_out. fp32 in/out, fp16 MFMA internally (threshold 7.5e-2).
// R15 (263.2us): flash KT=128 + raw v_exp_f32.
// R18 (260.3us): flash XCD head-grouping -> flash FETCH 146->25MB, ~64us.
// R19 (258.5us): gemm_qkv BK=64 + XOR-chunk swizzle -> <63.7us (was 74.5).
//      Dispatch sum ~166us vs total 258.5 -> ~90us inter-launch overhead
//      across 6 nodes (~13us/boundary).
// R20: (a) FUSE the 3 prep kernels (cast + 2 transposes, independent,
//      all 256-thr) into ONE launch via blockIdx partition — deletes 2
//      launch boundaries. (b) Port BK=64+swizzle to gemm_out (exact R19
//      transform; 16 iters, LDS 32KB). No sync-structure changes.
// R21-R25: resubmits (acquisition timeouts — infra, no kernel signal).
// ---------------------------------------------------------------------------

#define D_MODEL 1024
#define NHEADS  16
#define DHEAD   64
#define BATCH   4
#define SEQ     2048

typedef __attribute__((ext_vector_type(8))) _Float16 half8;
typedef __attribute__((ext_vector_type(4))) _Float16 half4;
typedef __attribute__((ext_vector_type(4))) float    f32x4;

__device__ __forceinline__ void async_copy16(const _Float16* g, _Float16* l) {
    __builtin_amdgcn_global_load_lds(
        (const __attribute__((address_space(1))) uint32_t*)g,
        (__attribute__((address_space(3))) uint32_t*)l, 16, 0, 0);
}

__device__ __forceinline__ float fast_exp2(float x) {
#if __has_builtin(__builtin_amdgcn_exp2f)
    return __builtin_amdgcn_exp2f(x);   // raw v_exp_f32; -inf -> 0
#else
    return exp2f(x);
#endif
}

// ---------------------------------------------------------------------------
// 1. fused prep: cast x -> Xh  |  transpose_cast Wqkv -> WqT  |  Wout -> WoT
//    blockIdx partition: [0,8192) cast; [8192,11264) Wqkv^T; [11264,12288)
//    Wout^T. All jobs independent, disjoint outputs; barrier is per-block.
// ---------------------------------------------------------------------------
__global__ void prep(const float* __restrict__ x,  _Float16* __restrict__ Xh,
                     const float* __restrict__ Wq, _Float16* __restrict__ WqT,
                     const float* __restrict__ Wo, _Float16* __restrict__ WoT) {
    __shared__ float tile[32][33];
    const int blk = blockIdx.x, tid = threadIdx.x;

    if (blk < 8192) {                       // cast path
        const size_t i = (size_t)blk * 256 + tid;
        float4 v = *(const float4*)(x + i * 4);
        half4 o;
        o.x = (_Float16)v.x; o.y = (_Float16)v.y;
        o.z = (_Float16)v.z; o.w = (_Float16)v.w;
        *(half4*)(Xh + i * 4) = o;
        return;
    }

    const float* in; _Float16* out; int R, C, bx, by;
    if (blk < 8192 + 3072) {                // Wqkv: 1024 x 3072 -> 3072 x 1024
        const int b = blk - 8192;
        in = Wq; out = WqT; R = 1024; C = 3072; bx = b % 96; by = b / 96;
    } else {                                // Wout: 1024 x 1024 -> 1024 x 1024
        const int b = blk - 8192 - 3072;
        in = Wo; out = WoT; R = 1024; C = 1024; bx = b % 32; by = b / 32;
    }
    const int tx = tid & 31, ty = tid >> 5;       // 32 x 8
    const int c0 = bx * 32, r0 = by * 32;
    #pragma unroll
    for (int i = 0; i < 32; i += 8)
        tile[ty + i][tx] = in[(size_t)(r0 + ty + i) * C + c0 + tx];
    __syncthreads();
    #pragma unroll
    for (int i = 0; i < 32; i += 8)
        out[(size_t)(c0 + ty + i) * R + r0 + tx] = (_Float16)tile[tx][ty + i];
}

// ---------------------------------------------------------------------------
// 2. QKV GEMM: Xh[8192][1024] @ WqT[3072][1024]^T.  BK=64, 16 K-iters.
//    A/B tiles 128x64 fp16, XOR-chunk-swizzled (LDS[r][c]=G[r][c^(r&7)]).
//    Cols < 2048 (Q,K) -> QK[8192][2048] row-major (direct stores).
//    Cols >= 2048 (V)  -> Vtg[(b*16+h)*64+d][2048] transposed, via an LDS
//    128x132 transpose so global stores are 16B-coalesced rows.
// ---------------------------------------------------------------------------
__global__ void gemm_qkv(const _Float16* __restrict__ A,
                         const _Float16* __restrict__ Bt,
                         _Float16* __restrict__ QK,
                         _Float16* __restrict__ Vtg) {
    __shared__ __attribute__((aligned(16))) _Float16 smem[128 * 132];
    _Float16* As = smem;            // 128 x 64, chunk-swizzled (16KB)
    _Float16* Bs = smem + 8192;     // 128 x 64, chunk-swizzled (16KB)

    const int tid  = threadIdx.x;
    const int w    = tid >> 6, lane = tid & 63;
    const int l15  = lane & 15, quad = lane >> 4;
    const int wm   = w >> 1, wn = w & 1;
    const int row0 = blockIdx.y * 128, col0 = blockIdx.x * 128;
    const int K = 1024;

    f32x4 acc[4][4];
    #pragma unroll
    for (int i = 0; i < 4; i++)
        #pragma unroll
        for (int j = 0; j < 4; j++)
            acc[i][j] = (f32x4){0.f, 0.f, 0.f, 0.f};

    const int lr  = lane >> 3;        // row 0..7 within wave's 8-row band
    const int src = (lane & 7) ^ lr;  // pre-swizzled source chunk (8 halfs)

    for (int k0 = 0; k0 < K; k0 += 64) {
        __syncthreads();
        #pragma unroll
        for (int q = 0; q < 4; q++) {
            async_copy16(A  + (size_t)(row0 + q * 32 + w * 8 + lr) * K + k0 + src * 8,
                         &As[(q * 32 + w * 8) * 64]);
            async_copy16(Bt + (size_t)(col0 + q * 32 + w * 8 + lr) * K + k0 + src * 8,
                         &Bs[(q * 32 + w * 8) * 64]);
        }
        __syncthreads();

        half8 af[2][4], bfm[2][4];
        #pragma unroll
        for (int i = 0; i < 4; i++) {
            const int ar = wm * 64 + i * 16 + l15;
            const int rs = ar & 7;
            #pragma unroll
            for (int kk = 0; kk < 2; kk++)
                af[kk][i] = *(const half8*)&As[ar * 64 + ((kk * 4 + quad) ^ rs) * 8];
        }
        #pragma unroll
        for (int j = 0; j < 4; j++) {
            const int br = wn * 64 + j * 16 + l15;
            const int rs = br & 7;
            #pragma unroll
            for (int kk = 0; kk < 2; kk++)
                bfm[kk][j] = *(const half8*)&Bs[br * 64 + ((kk * 4 + quad) ^ rs) * 8];
        }
        #pragma unroll
        for (int kk = 0; kk < 2; kk++)
            #pragma unroll
            for (int i = 0; i < 4; i++)
                #pragma unroll
                for (int j = 0; j < 4; j++)
                    acc[i][j] = __builtin_amdgcn_mfma_f32_16x16x32_f16(
                        af[kk][i], bfm[kk][j], acc[i][j], 0, 0, 0);
    }

    if (blockIdx.x < 16) {  // Q,K region: row-major into QK (ld 2048)
        #pragma unroll
        for (int i = 0; i < 4; i++) {
            int row = row0 + wm * 64 + i * 16 + quad * 4;
            #pragma unroll
            for (int j = 0; j < 4; j++) {
                int col = col0 + wn * 64 + j * 16 + l15;
                #pragma unroll
                for (int r = 0; r < 4; r++)
                    QK[(size_t)(row + r) * 2048 + col] = (_Float16)acc[i][j][r];
            }
        }
    } else {
        // V region: transpose 128x128 tile through LDS, then coalesced rows.
        __syncthreads();
        #pragma unroll
        for (int i = 0; i < 4; i++) {
            int tl = wm * 64 + i * 16 + quad * 4;
            #pragma unroll
            for (int j = 0; j < 4; j++) {
                int vl = wn * 64 + j * 16 + l15;
                half4 pk;
                #pragma unroll
                for (int r = 0; r < 4; r++) pk[r] = (_Float16)acc[i][j][r];
                *(half4*)&smem[vl * 132 + tl] = pk;
            }
        }
        __syncthreads();
        const int bb = row0 >> 11, tb = row0 & 2047;
        const int rr0 = tid >> 4;
        const int cc  = (tid & 15) * 8;
        #pragma unroll
        for (int s = 0; s < 8; s++) {
            int vl = rr0 + s * 16;
            int vcol = (col0 - 2048) + vl;
            int hh = vcol >> 6, d = vcol & 63;
            *(half8*)&Vtg[((size_t)((bb * 16 + hh) * 64 + d)) * 2048 + tb + cc] =
                *(const half8*)&smem[vl * 132 + cc];
        }
    }
}

// ---------------------------------------------------------------------------
// 3. output GEMM: Obuf[8192][1024] @ WoT[1024][1024]^T -> fp32 out.
//    BK=64 + XOR-chunk swizzle (same transform as gemm_qkv R19); 16 iters.
// ---------------------------------------------------------------------------
__global__ void gemm_out(const _Float16* __restrict__ A,
                         const _Float16* __restrict__ Bt,
                         float* __restrict__ Cf, int N, int K) {
    __shared__ __attribute__((aligned(16))) _Float16 smem[128 * 128];
    _Float16* As = smem;            // 128 x 64, chunk-swizzled (16KB)
    _Float16* Bs = smem + 8192;     // 128 x 64, chunk-swizzled (16KB)

    const int tid  = threadIdx.x;
    const int w    = tid >> 6, lane = tid & 63;
    const int l15  = lane & 15, quad = lane >> 4;
    const int wm   = w >> 1, wn = w & 1;
    const int row0 = blockIdx.y * 128, col0 = blockIdx.x * 128;

    f32x4 acc[4][4];
    #pragma unroll
    for (int i = 0; i < 4; i++)
        #pragma unroll
        for (int j = 0; j < 4; j++)
            acc[i][j] = (f32x4){0.f, 0.f, 0.f, 0.f};

    const int lr  = lane >> 3;
    const int src = (lane & 7) ^ lr;

    for (int k0 = 0; k0 < K; k0 += 64) {
        __syncthreads();
        #pragma unroll
        for (int q = 0; q < 4; q++) {
            async_copy16(A  + (size_t)(row0 + q * 32 + w * 8 + lr) * K + k0 + src * 8,
                         &As[(q * 32 + w * 8) * 64]);
            async_copy16(Bt + (size_t)(col0 + q * 32 + w * 8 + lr) * K + k0 + src * 8,
                         &Bs[(q * 32 + w * 8) * 64]);
        }
        __syncthreads();

        half8 af[2][4], bfm[2][4];
        #pragma unroll
        for (int i = 0; i < 4; i++) {
            const int ar = wm * 64 + i * 16 + l15;
            const int rs = ar & 7;
            #pragma unroll
            for (int kk = 0; kk < 2; kk++)
                af[kk][i] = *(const half8*)&As[ar * 64 + ((kk * 4 + quad) ^ rs) * 8];
        }
        #pragma unroll
        for (int j = 0; j < 4; j++) {
            const int br = wn * 64 + j * 16 + l15;
            const int rs = br & 7;
            #pragma unroll
            for (int kk = 0; kk < 2; kk++)
                bfm[kk][j] = *(const half8*)&Bs[br * 64 + ((kk * 4 + quad) ^ rs) * 8];
        }
        #pragma unroll
        for (int kk = 0; kk < 2; kk++)
            #pragma unroll
            for (int i = 0; i < 4; i++)
                #pragma unroll
                for (int j = 0; j < 4; j++)
                    acc[i][j] = __builtin_amdgcn_mfma_f32_16x16x32_f16(
                        af[kk][i], bfm[kk][j], acc[i][j], 0, 0, 0);
    }

    #pragma unroll
    for (int i = 0; i < 4; i++) {
        int row = row0 + wm * 64 + i * 16 + quad * 4;
        #pragma unroll
        for (int j = 0; j < 4; j++) {
            int col = col0 + wn * 64 + j * 16 + l15;
            #pragma unroll
            for (int r = 0; r < 4; r++)
                Cf[(size_t)(row + r) * N + col] = acc[i][j][r];
        }
    }
}

// ---------------------------------------------------------------------------
// 4. Flash attention (causal). QT=128 per block, 4 waves x 256 thr,
//    wave = 32 q rows (2 groups), KT=128 (17 iters). Pairing (pr, 15-pr);
//    grid dim3(NHEADS, 8, BATCH): h = blockIdx.x so XCD = h%8 — all 8
//    q-tile blocks of a head co-locate on one XCD (K/V L2-resident).
//    Proven sync template per iter: {bar; ds_write K/V tile; bar;
//    reg-prefetch next tile; compute}. K tile 128x64 (rows=kv), V tile
//    64x128 (rows=d). Q pre-scaled by log2(e)/8; raw v_exp_f32;
//    cvt_pkrtz P-packing; setprio around MFMA. S^T layout (A=K, B=Q).
//    QK processed in two nt-halves to cap st liveness.
// ---------------------------------------------------------------------------
#define PREFETCH(t)                                                          \
    do {                                                                     \
        const _Float16* kp_ = kb + (size_t)((t) * 128 + srow) * 2048 + sc;   \
        kr0 = *(const half8*)kp_;                                            \
        kr1 = *(const half8*)(kp_ + (size_t)32 * 2048);                      \
        kr2 = *(const half8*)(kp_ + (size_t)64 * 2048);                      \
        kr3 = *(const half8*)(kp_ + (size_t)96 * 2048);                      \
        const _Float16* vp_ = vb + (size_t)srow * 2048 + (t) * 128 + sc;     \
        vr0 = *(const half8*)vp_;                                            \
        vr1 = *(const half8*)(vp_ + 64);                                     \
        vr2 = *(const half8*)(vp_ + (size_t)32 * 2048);                      \
        vr3 = *(const half8*)(vp_ + (size_t)32 * 2048 + 64);                 \
    } while (0)

__global__ __launch_bounds__(256, 2) void flash_attn(
        const _Float16* __restrict__ qk, const _Float16* __restrict__ vt,
        _Float16* __restrict__ obuf) {
    const int h = blockIdx.x, pr = blockIdx.y, b = blockIdx.z;  // XCD = h%8
    const int tid = threadIdx.x;
    const int w = tid >> 6, lane = tid & 63;
    const int l15 = lane & 15, quad = lane >> 4;

    __shared__ __attribute__((aligned(16))) _Float16 Ks[128 * 72];   // rows=kv, cols=d
    __shared__ __attribute__((aligned(16))) _Float16 Vs[64 * 136];   // rows=d,  cols=kv
    __shared__ __attribute__((aligned(16))) _Float16 Pl[4][32 * 136];

    const _Float16* kb = qk + (size_t)b * SEQ * 2048 + D_MODEL + h * 64;
    const _Float16* vb = vt + (size_t)(b * 16 + h) * 64 * 2048;

    const int srow = tid >> 3;        // staging row 0..31 (+32/64/96)
    const int sc   = (tid & 7) * 8;   // 16B chunk within 64-elem row

    const _Float16 QSCL = (_Float16)0.18033688f;  // log2(e)/sqrt(64)

    #pragma unroll 1
    for (int phase = 0; phase < 2; ++phase) {
        const int tq = phase ? (15 - pr) : pr;
        const int q0 = tq * 128;
        const int n_iter = tq + 1;          // KT=128 tiles

        // Q as MFMA B-frag: B[n=q][k=d], 2 groups x 2 k-frags, pre-scaled
        half8 qf[2][2];
        #pragma unroll
        for (int g = 0; g < 2; g++) {
            const _Float16* qp = qk
                + ((size_t)(b * SEQ + q0 + w * 32 + g * 16 + l15)) * 2048
                + h * DHEAD + quad * 8;
            qf[g][0] = *(const half8*)qp;
            qf[g][1] = *(const half8*)(qp + 32);
            #pragma unroll
            for (int j = 0; j < 8; j++) {
                qf[g][0][j] *= QSCL;
                qf[g][1][j] *= QSCL;
            }
        }

        f32x4 o[2][4];
        float l_acc[2] = {0.f, 0.f};
        #pragma unroll
        for (int g = 0; g < 2; g++)
            #pragma unroll
            for (int d = 0; d < 4; d++) o[g][d] = (f32x4){0.f, 0.f, 0.f, 0.f};

        half8 kr0, kr1, kr2, kr3, vr0, vr1, vr2, vr3;
        PREFETCH(0);   // tile 0 into regs

        #pragma unroll 1
        for (int it = 0; it < n_iter; ++it) {
            __syncthreads();
            *(half8*)&Ks[(srow      ) * 72 + sc] = kr0;
            *(half8*)&Ks[(srow + 32 ) * 72 + sc] = kr1;
            *(half8*)&Ks[(srow + 64 ) * 72 + sc] = kr2;
            *(half8*)&Ks[(srow + 96 ) * 72 + sc] = kr3;
            *(half8*)&Vs[srow * 136 + sc]             = vr0;
            *(half8*)&Vs[srow * 136 + sc + 64]        = vr1;
            *(half8*)&Vs[(srow + 32) * 136 + sc]      = vr2;
            *(half8*)&Vs[(srow + 32) * 136 + sc + 64] = vr3;
            __syncthreads();

            if (it + 1 < n_iter) PREFETCH(it + 1);

            // S^T = K Q^T, two nt-halves of 4 (kv 0..63, 64..127); K frags
            // read once per half, reused across both q-groups.
            #pragma unroll
            for (int hh = 0; hh < 2; hh++) {
                f32x4 st[2][4];
                __builtin_amdgcn_s_setprio(1);
                #pragma unroll
                for (int n4 = 0; n4 < 4; n4++) {
                    const int nt = hh * 4 + n4;
                    half8 ka0 = *(const half8*)&Ks[(nt * 16 + l15) * 72 + quad * 8];
                    half8 ka1 = *(const half8*)&Ks[(nt * 16 + l15) * 72 + 32 + quad * 8];
                    #pragma unroll
                    for (int g = 0; g < 2; g++) {
                        f32x4 acc = (f32x4){0.f, 0.f, 0.f, 0.f};
                        acc = __builtin_amdgcn_mfma_f32_16x16x32_f16(ka0, qf[g][0], acc, 0, 0, 0);
                        acc = __builtin_amdgcn_mfma_f32_16x16x32_f16(ka1, qf[g][1], acc, 0, 0, 0);
                        st[g][n4] = acc;
                    }
                }
                __builtin_amdgcn_s_setprio(0);

                // causal mask (partial tiles only) + exp2 + P -> LDS (b64).
                // Dead groups fall into the mask path and store zeros.
                #pragma unroll
                for (int g = 0; g < 2; g++) {
                    const int c0 = __builtin_amdgcn_readfirstlane(
                        q0 + w * 32 + g * 16 - 128 * it);
                    if (c0 < 127) {
                        #pragma unroll
                        for (int n4 = 0; n4 < 4; n4++)
                            #pragma unroll
                            for (int r = 0; r < 4; r++)
                                if ((hh * 4 + n4) * 16 + quad * 4 + r - l15 > c0)
                                    st[g][n4][r] = -INFINITY;
                    }
                    #pragma unroll
                    for (int n4 = 0; n4 < 4; n4++) {
                        const int nt = hh * 4 + n4;
                        float p0 = fast_exp2(st[g][n4][0]);
                        float p1 = fast_exp2(st[g][n4][1]);
                        float p2 = fast_exp2(st[g][n4][2]);
                        float p3 = fast_exp2(st[g][n4][3]);
                        l_acc[g] += (p0 + p1) + (p2 + p3);
                        auto lo = __builtin_amdgcn_cvt_pkrtz(p0, p1);
                        auto hi = __builtin_amdgcn_cvt_pkrtz(p2, p3);
                        half4 pk;
                        pk[0] = (_Float16)lo[0]; pk[1] = (_Float16)lo[1];
                        pk[2] = (_Float16)hi[0]; pk[3] = (_Float16)hi[1];
                        *(half4*)&Pl[w][(g * 16 + l15) * 136 + nt * 16 + quad * 4] = pk;
                    }
                }
            }
            asm volatile("s_waitcnt lgkmcnt(0)" ::: "memory");  // same-wave RAW

            // O += P V : V frags read once, reused across both q-groups.
            __builtin_amdgcn_s_setprio(1);
            #pragma unroll
            for (int kf = 0; kf < 4; kf++) {
                half8 pf0 = *(const half8*)&Pl[w][l15 * 136 + kf * 32 + quad * 8];
                half8 pf1 = *(const half8*)&Pl[w][(16 + l15) * 136 + kf * 32 + quad * 8];
                #pragma unroll
                for (int dt = 0; dt < 4; dt++) {
                    half8 vf = *(const half8*)&Vs[(dt * 16 + l15) * 136 + kf * 32 + quad * 8];
                    o[0][dt] = __builtin_amdgcn_mfma_f32_16x16x32_f16(pf0, vf, o[0][dt], 0, 0, 0);
                    o[1][dt] = __builtin_amdgcn_mfma_f32_16x16x32_f16(pf1, vf, o[1][dt], 0, 0, 0);
                }
            }
            __builtin_amdgcn_s_setprio(0);
        }

        // epilogue per group: reduce l over quads, divide, store fp16
        #pragma unroll
        for (int g = 0; g < 2; g++) {
            float l = l_acc[g];
            l += __shfl_xor(l, 16);
            l += __shfl_xor(l, 32);   // every lane: L[q = l15]
            float linv[4];
            #pragma unroll
            for (int r = 0; r < 4; r++)
                linv[r] = 1.0f / __shfl(l, quad * 4 + r, 16);

            _Float16* ob = obuf
                + ((size_t)(b * SEQ + q0 + w * 32 + g * 16 + quad * 4)) * D_MODEL
                + h * DHEAD;
            #pragma unroll
            for (int r = 0; r < 4; r++) {
                #pragma unroll
                for (int dt = 0; dt < 4; dt++)
                    ob[(size_t)r * D_MODEL + dt * 16 + l15] =
                        (_Float16)(o[g][dt][r] * linv[r]);
            }
        }
        __syncthreads();  // protect Ks/Vs before next phase's first stage
    }
}

// ---------------------------------------------------------------------------
// launch
// ---------------------------------------------------------------------------
extern "C" void kernel_launch(void* const* d_in, const int* in_sizes, int n_in,
                              void* d_out, int out_size, void* d_ws, size_t ws_size,
                              hipStream_t stream) {
    const float* x    = (const float*)d_in[0];
    const float* Wqkv = (const float*)d_in[1];
    const float* Wout = (const float*)d_in[2];
    float* out = (float*)d_out;

    char* ws = (char*)d_ws;
    _Float16* Xh   = (_Float16*)(ws);                          // 16 MB
    _Float16* WqT  = (_Float16*)(ws + ((size_t)16 << 20));     //  6 MB
    _Float16* WoT  = (_Float16*)(ws + ((size_t)23 << 20));     //  2 MB
    _Float16* QKb  = (_Float16*)(ws + ((size_t)26 << 20));     // 32 MB
    _Float16* Vtg  = (_Float16*)(ws + ((size_t)58 << 20));     // 16 MB
    _Float16* Obuf = (_Float16*)(ws + ((size_t)74 << 20));     // 16 MB -> 90 MB

    prep<<<8192 + 3072 + 1024, 256, 0, stream>>>(x, Xh, Wqkv, WqT, Wout, WoT);
    gemm_qkv<<<dim3(24, 64), 256, 0, stream>>>(Xh, WqT, QKb, Vtg);
    flash_attn<<<dim3(NHEADS, 8, BATCH), 256, 0, stream>>>(QKb, Vtg, Obuf);
    gemm_out<<<dim3(8, 64), 256, 0, stream>>>(Obuf, WoT, out, 1024, 1024);
}